// Round 5
// baseline (247.359 us; speedup 1.0000x reference)
//
#include <hip/hip_runtime.h>
#include <hip/hip_bf16.h>

// DisenHAN fused, MFMA split-bf16 edition, v2 (gfx950).
// Round-5 change: weight matrices are pre-split (hi/lo bf16) and pre-swizzled
// into MFMA B-fragment order by a tiny setup kernel into d_ws. The main
// kernel's load_wfrag is 16 coalesced 16B loads (was 192 scalar loads +
// ~1500 VALU conversion ops per lane, redundant across 4096 blocks).
// One 256-thread block per (batch, branch); wave w owns s-slots 4w..4w+3.
// 3-pass split-bf16 MFMA: A_hi*W_hi + A_lo*W_hi + A_hi*W_lo (~fp32 accuracy).
// Routing softmax register+shuffle; single __syncthreads. T=1 collapses
// hete-attention: beta==1, wp==1 forever.

#define NTH 256

typedef __attribute__((ext_vector_type(8))) short bf16x8;   // 8 bf16 (4 VGPRs)
typedef __attribute__((ext_vector_type(4))) float floatx4;

__device__ __forceinline__ short f2bf(float f) {            // RNE fp32->bf16
    unsigned u = __builtin_bit_cast(unsigned, f);
    unsigned r = u + 0x7fffu + ((u >> 16) & 1u);
    return (short)(r >> 16);
}
__device__ __forceinline__ float bf2f_s(short h) {
    return __builtin_bit_cast(float, (unsigned)((unsigned short)h) << 16);
}

// split x -> hi + lo bf16 (hi=RNE(x), lo=RNE(x-hi)); ~16 mantissa bits total
__device__ __forceinline__ void split_pack8(float4 a, float4 b, bf16x8& hi, bf16x8& lo) {
    float v[8] = {a.x, a.y, a.z, a.w, b.x, b.y, b.z, b.w};
#pragma unroll
    for (int i = 0; i < 8; ++i) {
        short h = f2bf(v[i]);
        hi[i] = h;
        lo[i] = f2bf(v[i] - bf2f_s(h));
    }
}

__device__ __forceinline__ floatx4 mfma3(bf16x8 Ah, bf16x8 Al, bf16x8 Wh, bf16x8 Wl,
                                         floatx4 acc) {
    acc = __builtin_amdgcn_mfma_f32_16x16x32_bf16(Ah, Wh, acc, 0, 0, 0);
    acc = __builtin_amdgcn_mfma_f32_16x16x32_bf16(Al, Wh, acc, 0, 0, 0);
    acc = __builtin_amdgcn_mfma_f32_16x16x32_bf16(Ah, Wl, acc, 0, 0, 0);
    return acc;
}

// ---- setup: pack 4 weight matrices into B-fragment order, hi/lo split ----
// layout: frag16[ ((w*4+nt)*2+ks)*2+h ][ lane ] = 8 bf16 (16B), coalesced.
__global__ void pack_weights(const float* __restrict__ W0u, const float* __restrict__ W0i,
                             const float* __restrict__ W1u, const float* __restrict__ W1i,
                             short* __restrict__ pk) {
    const float* Ws[4] = {W0u, W0i, W1u, W1i};
    const int w = blockIdx.x;
    const int lane = threadIdx.x;       // 64
    const int quad = lane >> 4, m16 = lane & 15;
    const float* W = Ws[w];
#pragma unroll
    for (int nt = 0; nt < 4; ++nt)
#pragma unroll
        for (int ks = 0; ks < 2; ++ks) {
            bf16x8 fh, fl;
#pragma unroll
            for (int j = 0; j < 8; ++j) {
                float x = W[(ks * 32 + quad * 8 + j) * 64 + nt * 16 + m16];
                short h = f2bf(x);
                fh[j] = h;
                fl[j] = f2bf(x - bf2f_s(h));
            }
            long base = (long)(((w * 4 + nt) * 2 + ks) * 2) * 64 + lane;
            ((bf16x8*)pk)[base] = fh;         // h=0 (hi)
            ((bf16x8*)pk)[base + 64] = fl;    // h=1 (lo)
        }
}

__global__ __launch_bounds__(256, 4)
void disenhan_mfma(const float* __restrict__ user_table,
                   const float* __restrict__ item_table,
                   const bf16x8* __restrict__ pk,
                   const int* __restrict__ uidx0, const int* __restrict__ uidx1,
                   const int* __restrict__ uidx2,
                   const int* __restrict__ iidx0, const int* __restrict__ iidx1,
                   const int* __restrict__ iidx2,
                   float* __restrict__ out, int B)
{
    constexpr float SCALE = 0.35355339059327373f;  // 1/sqrt(8)
    const int b = blockIdx.x, branch = blockIdx.y;
    const int tid = threadIdx.x;
    const int wv = tid >> 6, lane = tid & 63;
    const int quad = lane >> 4;   // MFMA k-block selector
    const int m16  = lane & 15;   // MFMA row (A) / col (B,D) selector

    // matrix ids in pk: 0=W0u 1=W0i 2=W1u 3=W1i
    const float *tab0, *tab1;
    const int *idx0, *idx1, *idx2;
    int w1c_id, w1n_id, w0n_id;
    if (branch == 0) { tab0 = user_table; tab1 = item_table;
                       idx0 = uidx0; idx1 = uidx1; idx2 = uidx2;
                       w1c_id = 3; w1n_id = 2; w0n_id = 1; }
    else             { tab0 = item_table; tab1 = user_table;
                       idx0 = iidx0; idx1 = iidx1; idx2 = iidx2;
                       w1c_id = 2; w1n_id = 3; w0n_id = 0; }

    __shared__ float sN[4][16 * 68];  // per-wave nh tile (fp32, pitch 68)
    __shared__ float sC[16 * 68];     // hid (= c), pitch 68
    __shared__ float sH[16 * 68];     // htmp / h1, pitch 68
    __shared__ float sA[4][16 * 9];   // per-wave attention weights [n][k], pitch 9
    __shared__ float sE0[64];         // layer-0 center (e0)
    __shared__ float sH0[68];         // layer-0 htmp

    // e0 prefetch (consumed by wave 0 at the end; loaded by all, uniform)
    const float v0 = tab0[(long)idx0[b] * 64 + lane];

    // ---- B-fragment loader: 16 coalesced 16B loads from the packed buffer ----
    bf16x8 wfh[4][2], wfl[4][2];
    auto load_wfrag = [&](int w) {
#pragma unroll
        for (int nt = 0; nt < 4; ++nt)
#pragma unroll
            for (int ks = 0; ks < 2; ++ks) {
                long base = (long)(((w * 4 + nt) * 2 + ks) * 2) * 64 + lane;
                wfh[nt][ks] = pk[base];
                wfl[nt][ks] = pk[base + 64];
            }
    };

    // ---- routing: 3 iterations on one s-slot, intra-wave only ----
    auto routing = [&](const float* __restrict__ Nw, float* __restrict__ Hrow,
                       const float* __restrict__ Crow, float* __restrict__ Arow,
                       bool relu_last, float* __restrict__ outp) {
        const int mm = lane >> 3, kk = lane & 7;          // logits: n=mm,mm+8 ; facet kk
        const int r = lane >> 4, j4 = lane & 15, k2 = j4 >> 1;  // update mapping
#pragma unroll
        for (int it = 0; it < 3; ++it) {
            float4 ha = *(const float4*)&Hrow[kk * 8];
            float4 hb = *(const float4*)&Hrow[kk * 8 + 4];
            float4 na = *(const float4*)&Nw[mm * 68 + kk * 8];
            float4 nb = *(const float4*)&Nw[mm * 68 + kk * 8 + 4];
            float4 nc = *(const float4*)&Nw[(mm + 8) * 68 + kk * 8];
            float4 nd = *(const float4*)&Nw[(mm + 8) * 68 + kk * 8 + 4];
            float l0 = (ha.x*na.x + ha.y*na.y + ha.z*na.z + ha.w*na.w +
                        hb.x*nb.x + hb.y*nb.y + hb.z*nb.z + hb.w*nb.w) * SCALE;
            float l1 = (ha.x*nc.x + ha.y*nc.y + ha.z*nc.z + ha.w*nc.w +
                        hb.x*nd.x + hb.y*nd.y + hb.z*nd.z + hb.w*nd.w) * SCALE;
            float mx = fmaxf(l0, l1);
            mx = fmaxf(mx, __shfl_xor(mx, 8));
            mx = fmaxf(mx, __shfl_xor(mx, 16));
            mx = fmaxf(mx, __shfl_xor(mx, 32));
            float e0 = __expf(l0 - mx), e1 = __expf(l1 - mx);
            float sm = e0 + e1;
            sm += __shfl_xor(sm, 8); sm += __shfl_xor(sm, 16); sm += __shfl_xor(sm, 32);
            float inv = 1.0f / sm;
            Arow[mm * 9 + kk] = e0 * inv;
            Arow[(mm + 8) * 9 + kk] = e1 * inv;
            __builtin_amdgcn_wave_barrier();
            // z[j] = sum_n a[n][k(j)] * N[n][j] ; 4 n's per replica r, shuffle-reduced
            float4 z = {0.f, 0.f, 0.f, 0.f};
#pragma unroll
            for (int t = 0; t < 4; ++t) {
                float a = Arow[(4 * r + t) * 9 + k2];
                float4 nv = *(const float4*)&Nw[(4 * r + t) * 68 + j4 * 4];
                z.x = fmaf(a, nv.x, z.x); z.y = fmaf(a, nv.y, z.y);
                z.z = fmaf(a, nv.z, z.z); z.w = fmaf(a, nv.w, z.w);
            }
            z.x += __shfl_xor(z.x, 16); z.y += __shfl_xor(z.y, 16);
            z.z += __shfl_xor(z.z, 16); z.w += __shfl_xor(z.w, 16);
            z.x += __shfl_xor(z.x, 32); z.y += __shfl_xor(z.y, 32);
            z.z += __shfl_xor(z.z, 32); z.w += __shfl_xor(z.w, 32);
            if (r == 0) {
                float4 c = *(const float4*)&Crow[j4 * 4];
                float4 h = {c.x + z.x, c.y + z.y, c.z + z.z, c.w + z.w};
                if (relu_last && it == 2) {
                    h.x = fmaxf(h.x, 0.f); h.y = fmaxf(h.y, 0.f);
                    h.z = fmaxf(h.z, 0.f); h.w = fmaxf(h.w, 0.f);
                }
                *(float4*)&Hrow[j4 * 4] = h;
                if (outp && it == 2) *(float4*)&outp[j4 * 4] = h;
            }
            __builtin_amdgcn_wave_barrier();
        }
    };

    // ================= layer-1 pre-encode: hid = e1 @ W1c =================
    load_wfrag(w1c_id);
    {
        const long g1 = (long)idx1[b * 16 + m16] * 64;
        const float* p1 = &tab1[g1 + quad * 8];
        bf16x8 A0h, A0l, A1h, A1l;
        split_pack8(*(const float4*)p1, *(const float4*)(p1 + 4), A0h, A0l);
        split_pack8(*(const float4*)(p1 + 32), *(const float4*)(p1 + 36), A1h, A1l);
        floatx4 hacc[4];
#pragma unroll
        for (int nt = 0; nt < 4; ++nt) {
            hacc[nt] = (floatx4){0.f, 0.f, 0.f, 0.f};
            hacc[nt] = mfma3(A0h, A0l, wfh[nt][0], wfl[nt][0], hacc[nt]);
            hacc[nt] = mfma3(A1h, A1l, wfh[nt][1], wfl[nt][1], hacc[nt]);
        }
        // D: row = quad*4+reg, col = nt*16+m16. Wave w keeps its own rows.
        if (quad == wv) {
#pragma unroll
            for (int nt = 0; nt < 4; ++nt)
#pragma unroll
                for (int rg = 0; rg < 4; ++rg) {
                    int row = quad * 4 + rg, col = nt * 16 + m16;
                    float v = hacc[nt][rg];
                    sC[row * 68 + col] = v;
                    sH[row * 68 + col] = v;
                }
        }
    }

    // ================= layer-1 main: 4 s-slots per wave =================
    load_wfrag(w1n_id);
    int gidx[4];
#pragma unroll
    for (int q = 0; q < 4; ++q)
        gidx[q] = idx2[b * 256 + (wv * 4 + q) * 16 + m16];

    float4 f0, f1, f2, f3;
    {
        const float* p = &tab0[(long)gidx[0] * 64 + quad * 8];
        f0 = *(const float4*)p;        f1 = *(const float4*)(p + 4);
        f2 = *(const float4*)(p + 32); f3 = *(const float4*)(p + 36);
    }
#pragma unroll
    for (int q = 0; q < 4; ++q) {
        const int s = wv * 4 + q;
        bf16x8 A0h, A0l, A1h, A1l;
        split_pack8(f0, f1, A0h, A0l);
        split_pack8(f2, f3, A1h, A1l);
        if (q < 3) {  // prefetch next slot's A rows; consumed next iteration
            const float* p = &tab0[(long)gidx[q + 1] * 64 + quad * 8];
            f0 = *(const float4*)p;        f1 = *(const float4*)(p + 4);
            f2 = *(const float4*)(p + 32); f3 = *(const float4*)(p + 36);
        }
        floatx4 acc[4];
#pragma unroll
        for (int nt = 0; nt < 4; ++nt) {
            acc[nt] = (floatx4){0.f, 0.f, 0.f, 0.f};
            acc[nt] = mfma3(A0h, A0l, wfh[nt][0], wfl[nt][0], acc[nt]);
            acc[nt] = mfma3(A1h, A1l, wfh[nt][1], wfl[nt][1], acc[nt]);
        }
#pragma unroll
        for (int nt = 0; nt < 4; ++nt)
#pragma unroll
            for (int rg = 0; rg < 4; ++rg)
                sN[wv][(quad * 4 + rg) * 68 + nt * 16 + m16] = acc[nt][rg];
        __builtin_amdgcn_wave_barrier();
        routing(sN[wv], &sH[s * 68], &sC[s * 68], sA[wv], true, nullptr);
    }

    // ================= layer-0 =================
    __syncthreads();   // the only block barrier: all h1 rows visible
    if (wv == 0) {
        load_wfrag(w0n_id);
        sE0[lane] = v0;
        sH0[lane] = v0;
        bf16x8 A0h, A0l, A1h, A1l;
        {
            const float* hp = &sH[m16 * 68];
            split_pack8(*(const float4*)&hp[quad * 8],
                        *(const float4*)&hp[quad * 8 + 4], A0h, A0l);
            split_pack8(*(const float4*)&hp[32 + quad * 8],
                        *(const float4*)&hp[32 + quad * 8 + 4], A1h, A1l);
        }
        floatx4 acc[4];
#pragma unroll
        for (int nt = 0; nt < 4; ++nt) {
            acc[nt] = (floatx4){0.f, 0.f, 0.f, 0.f};
            acc[nt] = mfma3(A0h, A0l, wfh[nt][0], wfl[nt][0], acc[nt]);
            acc[nt] = mfma3(A1h, A1l, wfh[nt][1], wfl[nt][1], acc[nt]);
        }
#pragma unroll
        for (int nt = 0; nt < 4; ++nt)
#pragma unroll
            for (int rg = 0; rg < 4; ++rg)
                sN[0][(quad * 4 + rg) * 68 + nt * 16 + m16] = acc[nt][rg];
        __builtin_amdgcn_wave_barrier();
        routing(sN[0], sH0, sE0, sA[0], false, &out[((long)branch * B + b) * 64]);
    }
}

extern "C" void kernel_launch(void* const* d_in, const int* in_sizes, int n_in,
                              void* d_out, int out_size, void* d_ws, size_t ws_size,
                              hipStream_t stream) {
    const float* user_table = (const float*)d_in[0];
    const float* item_table = (const float*)d_in[1];
    const float* W0u = (const float*)d_in[2];
    const float* W0i = (const float*)d_in[3];
    const float* W1u = (const float*)d_in[4];
    const float* W1i = (const float*)d_in[5];
    const int* uidx0 = (const int*)d_in[6];
    const int* uidx1 = (const int*)d_in[7];
    const int* uidx2 = (const int*)d_in[8];
    const int* iidx0 = (const int*)d_in[9];
    const int* iidx1 = (const int*)d_in[10];
    const int* iidx2 = (const int*)d_in[11];
    float* out = (float*)d_out;
    short* pk = (short*)d_ws;   // 4 matrices * 16 frags * 64 lanes * 16B = 64 KB

    const int B = in_sizes[6];  // 2048
    hipLaunchKernelGGL(pack_weights, dim3(4), dim3(64), 0, stream,
                       W0u, W0i, W1u, W1i, pk);
    dim3 grid(B, 2), block(NTH);
    hipLaunchKernelGGL(disenhan_mfma, grid, block, 0, stream,
                       user_table, item_table, (const bf16x8*)pk,
                       uidx0, uidx1, uidx2, iidx0, iidx1, iidx2, out, B);
}

// Round 6
// 200.346 us; speedup vs baseline: 1.2347x; 1.2347x over previous
//
#include <hip/hip_runtime.h>
#include <hip/hip_bf16.h>

// DisenHAN fused, MFMA split-bf16 edition, v3 (gfx950).
// v3: revert launch_bounds to (256,3) — (256,4) capped VGPR at 128 and spilled
// ~270MB of scratch to HBM (round-5 counters: WRITE_SIZE 3->140MB). Keep the
// packed-weight path (pre-split hi/lo bf16 fragments in d_ws) and widen the
// pack kernel to 256 threads to cut its serialized latency.
// One 256-thread block per (batch, branch); wave w owns s-slots 4w..4w+3.
// 3-pass split-bf16 MFMA: A_hi*W_hi + A_lo*W_hi + A_hi*W_lo (~fp32 accuracy).
// Routing softmax register+shuffle; single __syncthreads. T=1 collapses
// hete-attention: beta==1, wp==1 forever.

#define NTH 256

typedef __attribute__((ext_vector_type(8))) short bf16x8;   // 8 bf16 (4 VGPRs)
typedef __attribute__((ext_vector_type(4))) float floatx4;

__device__ __forceinline__ short f2bf(float f) {            // RNE fp32->bf16
    unsigned u = __builtin_bit_cast(unsigned, f);
    unsigned r = u + 0x7fffu + ((u >> 16) & 1u);
    return (short)(r >> 16);
}
__device__ __forceinline__ float bf2f_s(short h) {
    return __builtin_bit_cast(float, (unsigned)((unsigned short)h) << 16);
}

// split x -> hi + lo bf16 (hi=RNE(x), lo=RNE(x-hi)); ~16 mantissa bits total
__device__ __forceinline__ void split_pack8(float4 a, float4 b, bf16x8& hi, bf16x8& lo) {
    float v[8] = {a.x, a.y, a.z, a.w, b.x, b.y, b.z, b.w};
#pragma unroll
    for (int i = 0; i < 8; ++i) {
        short h = f2bf(v[i]);
        hi[i] = h;
        lo[i] = f2bf(v[i] - bf2f_s(h));
    }
}

__device__ __forceinline__ floatx4 mfma3(bf16x8 Ah, bf16x8 Al, bf16x8 Wh, bf16x8 Wl,
                                         floatx4 acc) {
    acc = __builtin_amdgcn_mfma_f32_16x16x32_bf16(Ah, Wh, acc, 0, 0, 0);
    acc = __builtin_amdgcn_mfma_f32_16x16x32_bf16(Al, Wh, acc, 0, 0, 0);
    acc = __builtin_amdgcn_mfma_f32_16x16x32_bf16(Ah, Wl, acc, 0, 0, 0);
    return acc;
}

// ---- setup: pack 4 weight matrices into B-fragment order, hi/lo split ----
// layout: frag16[ ((w*4+nt)*2+ks)*2+h ][ lane ] = 8 bf16 (16B), coalesced.
// 256 threads/block: wave wv handles nt=wv (4x less serial latency than v2).
__global__ void pack_weights(const float* __restrict__ W0u, const float* __restrict__ W0i,
                             const float* __restrict__ W1u, const float* __restrict__ W1i,
                             short* __restrict__ pk) {
    const float* Ws[4] = {W0u, W0i, W1u, W1i};
    const int w = blockIdx.x;
    const int wv = threadIdx.x >> 6, lane = threadIdx.x & 63;
    const int quad = lane >> 4, m16 = lane & 15;
    const int nt = wv;
    const float* W = Ws[w];
#pragma unroll
    for (int ks = 0; ks < 2; ++ks) {
        bf16x8 fh, fl;
#pragma unroll
        for (int j = 0; j < 8; ++j) {
            float x = W[(ks * 32 + quad * 8 + j) * 64 + nt * 16 + m16];
            short h = f2bf(x);
            fh[j] = h;
            fl[j] = f2bf(x - bf2f_s(h));
        }
        long base = (long)(((w * 4 + nt) * 2 + ks) * 2) * 64 + lane;
        ((bf16x8*)pk)[base] = fh;         // h=0 (hi)
        ((bf16x8*)pk)[base + 64] = fl;    // h=1 (lo)
    }
}

__global__ __launch_bounds__(256, 3)
void disenhan_mfma(const float* __restrict__ user_table,
                   const float* __restrict__ item_table,
                   const bf16x8* __restrict__ pk,
                   const int* __restrict__ uidx0, const int* __restrict__ uidx1,
                   const int* __restrict__ uidx2,
                   const int* __restrict__ iidx0, const int* __restrict__ iidx1,
                   const int* __restrict__ iidx2,
                   float* __restrict__ out, int B)
{
    constexpr float SCALE = 0.35355339059327373f;  // 1/sqrt(8)
    const int b = blockIdx.x, branch = blockIdx.y;
    const int tid = threadIdx.x;
    const int wv = tid >> 6, lane = tid & 63;
    const int quad = lane >> 4;   // MFMA k-block selector
    const int m16  = lane & 15;   // MFMA row (A) / col (B,D) selector

    // matrix ids in pk: 0=W0u 1=W0i 2=W1u 3=W1i
    const float *tab0, *tab1;
    const int *idx0, *idx1, *idx2;
    int w1c_id, w1n_id, w0n_id;
    if (branch == 0) { tab0 = user_table; tab1 = item_table;
                       idx0 = uidx0; idx1 = uidx1; idx2 = uidx2;
                       w1c_id = 3; w1n_id = 2; w0n_id = 1; }
    else             { tab0 = item_table; tab1 = user_table;
                       idx0 = iidx0; idx1 = iidx1; idx2 = iidx2;
                       w1c_id = 2; w1n_id = 3; w0n_id = 0; }

    __shared__ float sN[4][16 * 68];  // per-wave nh tile (fp32, pitch 68)
    __shared__ float sC[16 * 68];     // hid (= c), pitch 68
    __shared__ float sH[16 * 68];     // htmp / h1, pitch 68
    __shared__ float sA[4][16 * 9];   // per-wave attention weights [n][k], pitch 9
    __shared__ float sE0[64];         // layer-0 center (e0)
    __shared__ float sH0[68];         // layer-0 htmp

    // e0 prefetch (consumed by wave 0 at the end; loaded by all, uniform)
    const float v0 = tab0[(long)idx0[b] * 64 + lane];

    // ---- B-fragment loader: 16 coalesced 16B loads from the packed buffer ----
    bf16x8 wfh[4][2], wfl[4][2];
    auto load_wfrag = [&](int w) {
#pragma unroll
        for (int nt = 0; nt < 4; ++nt)
#pragma unroll
            for (int ks = 0; ks < 2; ++ks) {
                long base = (long)(((w * 4 + nt) * 2 + ks) * 2) * 64 + lane;
                wfh[nt][ks] = pk[base];
                wfl[nt][ks] = pk[base + 64];
            }
    };

    // ---- routing: 3 iterations on one s-slot, intra-wave only ----
    auto routing = [&](const float* __restrict__ Nw, float* __restrict__ Hrow,
                       const float* __restrict__ Crow, float* __restrict__ Arow,
                       bool relu_last, float* __restrict__ outp) {
        const int mm = lane >> 3, kk = lane & 7;          // logits: n=mm,mm+8 ; facet kk
        const int r = lane >> 4, j4 = lane & 15, k2 = j4 >> 1;  // update mapping
#pragma unroll
        for (int it = 0; it < 3; ++it) {
            float4 ha = *(const float4*)&Hrow[kk * 8];
            float4 hb = *(const float4*)&Hrow[kk * 8 + 4];
            float4 na = *(const float4*)&Nw[mm * 68 + kk * 8];
            float4 nb = *(const float4*)&Nw[mm * 68 + kk * 8 + 4];
            float4 nc = *(const float4*)&Nw[(mm + 8) * 68 + kk * 8];
            float4 nd = *(const float4*)&Nw[(mm + 8) * 68 + kk * 8 + 4];
            float l0 = (ha.x*na.x + ha.y*na.y + ha.z*na.z + ha.w*na.w +
                        hb.x*nb.x + hb.y*nb.y + hb.z*nb.z + hb.w*nb.w) * SCALE;
            float l1 = (ha.x*nc.x + ha.y*nc.y + ha.z*nc.z + ha.w*nc.w +
                        hb.x*nd.x + hb.y*nd.y + hb.z*nd.z + hb.w*nd.w) * SCALE;
            float mx = fmaxf(l0, l1);
            mx = fmaxf(mx, __shfl_xor(mx, 8));
            mx = fmaxf(mx, __shfl_xor(mx, 16));
            mx = fmaxf(mx, __shfl_xor(mx, 32));
            float e0 = __expf(l0 - mx), e1 = __expf(l1 - mx);
            float sm = e0 + e1;
            sm += __shfl_xor(sm, 8); sm += __shfl_xor(sm, 16); sm += __shfl_xor(sm, 32);
            float inv = 1.0f / sm;
            Arow[mm * 9 + kk] = e0 * inv;
            Arow[(mm + 8) * 9 + kk] = e1 * inv;
            __builtin_amdgcn_wave_barrier();
            // z[j] = sum_n a[n][k(j)] * N[n][j] ; 4 n's per replica r, shuffle-reduced
            float4 z = {0.f, 0.f, 0.f, 0.f};
#pragma unroll
            for (int t = 0; t < 4; ++t) {
                float a = Arow[(4 * r + t) * 9 + k2];
                float4 nv = *(const float4*)&Nw[(4 * r + t) * 68 + j4 * 4];
                z.x = fmaf(a, nv.x, z.x); z.y = fmaf(a, nv.y, z.y);
                z.z = fmaf(a, nv.z, z.z); z.w = fmaf(a, nv.w, z.w);
            }
            z.x += __shfl_xor(z.x, 16); z.y += __shfl_xor(z.y, 16);
            z.z += __shfl_xor(z.z, 16); z.w += __shfl_xor(z.w, 16);
            z.x += __shfl_xor(z.x, 32); z.y += __shfl_xor(z.y, 32);
            z.z += __shfl_xor(z.z, 32); z.w += __shfl_xor(z.w, 32);
            if (r == 0) {
                float4 c = *(const float4*)&Crow[j4 * 4];
                float4 h = {c.x + z.x, c.y + z.y, c.z + z.z, c.w + z.w};
                if (relu_last && it == 2) {
                    h.x = fmaxf(h.x, 0.f); h.y = fmaxf(h.y, 0.f);
                    h.z = fmaxf(h.z, 0.f); h.w = fmaxf(h.w, 0.f);
                }
                *(float4*)&Hrow[j4 * 4] = h;
                if (outp && it == 2) *(float4*)&outp[j4 * 4] = h;
            }
            __builtin_amdgcn_wave_barrier();
        }
    };

    // ================= layer-1 pre-encode: hid = e1 @ W1c =================
    // issue the e1 gather loads BEFORE the fragment loads so latencies overlap
    const long g1 = (long)idx1[b * 16 + m16] * 64;
    const float* p1 = &tab1[g1 + quad * 8];
    float4 e1a = *(const float4*)p1;
    float4 e1b = *(const float4*)(p1 + 4);
    float4 e1c = *(const float4*)(p1 + 32);
    float4 e1d = *(const float4*)(p1 + 36);
    load_wfrag(w1c_id);
    {
        bf16x8 A0h, A0l, A1h, A1l;
        split_pack8(e1a, e1b, A0h, A0l);
        split_pack8(e1c, e1d, A1h, A1l);
        floatx4 hacc[4];
#pragma unroll
        for (int nt = 0; nt < 4; ++nt) {
            hacc[nt] = (floatx4){0.f, 0.f, 0.f, 0.f};
            hacc[nt] = mfma3(A0h, A0l, wfh[nt][0], wfl[nt][0], hacc[nt]);
            hacc[nt] = mfma3(A1h, A1l, wfh[nt][1], wfl[nt][1], hacc[nt]);
        }
        // D: row = quad*4+reg, col = nt*16+m16. Wave w keeps its own rows.
        if (quad == wv) {
#pragma unroll
            for (int nt = 0; nt < 4; ++nt)
#pragma unroll
                for (int rg = 0; rg < 4; ++rg) {
                    int row = quad * 4 + rg, col = nt * 16 + m16;
                    float v = hacc[nt][rg];
                    sC[row * 68 + col] = v;
                    sH[row * 68 + col] = v;
                }
        }
    }

    // ================= layer-1 main: 4 s-slots per wave =================
    int gidx[4];
#pragma unroll
    for (int q = 0; q < 4; ++q)
        gidx[q] = idx2[b * 256 + (wv * 4 + q) * 16 + m16];

    float4 f0, f1, f2, f3;
    {
        const float* p = &tab0[(long)gidx[0] * 64 + quad * 8];
        f0 = *(const float4*)p;        f1 = *(const float4*)(p + 4);
        f2 = *(const float4*)(p + 32); f3 = *(const float4*)(p + 36);
    }
    load_wfrag(w1n_id);
#pragma unroll
    for (int q = 0; q < 4; ++q) {
        const int s = wv * 4 + q;
        bf16x8 A0h, A0l, A1h, A1l;
        split_pack8(f0, f1, A0h, A0l);
        split_pack8(f2, f3, A1h, A1l);
        if (q < 3) {  // prefetch next slot's A rows; consumed next iteration
            const float* p = &tab0[(long)gidx[q + 1] * 64 + quad * 8];
            f0 = *(const float4*)p;        f1 = *(const float4*)(p + 4);
            f2 = *(const float4*)(p + 32); f3 = *(const float4*)(p + 36);
        }
        floatx4 acc[4];
#pragma unroll
        for (int nt = 0; nt < 4; ++nt) {
            acc[nt] = (floatx4){0.f, 0.f, 0.f, 0.f};
            acc[nt] = mfma3(A0h, A0l, wfh[nt][0], wfl[nt][0], acc[nt]);
            acc[nt] = mfma3(A1h, A1l, wfh[nt][1], wfl[nt][1], acc[nt]);
        }
#pragma unroll
        for (int nt = 0; nt < 4; ++nt)
#pragma unroll
            for (int rg = 0; rg < 4; ++rg)
                sN[wv][(quad * 4 + rg) * 68 + nt * 16 + m16] = acc[nt][rg];
        __builtin_amdgcn_wave_barrier();
        routing(sN[wv], &sH[s * 68], &sC[s * 68], sA[wv], true, nullptr);
    }

    // ================= layer-0 =================
    __syncthreads();   // the only block barrier: all h1 rows visible
    if (wv == 0) {
        load_wfrag(w0n_id);
        sE0[lane] = v0;
        sH0[lane] = v0;
        bf16x8 A0h, A0l, A1h, A1l;
        {
            const float* hp = &sH[m16 * 68];
            split_pack8(*(const float4*)&hp[quad * 8],
                        *(const float4*)&hp[quad * 8 + 4], A0h, A0l);
            split_pack8(*(const float4*)&hp[32 + quad * 8],
                        *(const float4*)&hp[32 + quad * 8 + 4], A1h, A1l);
        }
        floatx4 acc[4];
#pragma unroll
        for (int nt = 0; nt < 4; ++nt) {
            acc[nt] = (floatx4){0.f, 0.f, 0.f, 0.f};
            acc[nt] = mfma3(A0h, A0l, wfh[nt][0], wfl[nt][0], acc[nt]);
            acc[nt] = mfma3(A1h, A1l, wfh[nt][1], wfl[nt][1], acc[nt]);
        }
#pragma unroll
        for (int nt = 0; nt < 4; ++nt)
#pragma unroll
            for (int rg = 0; rg < 4; ++rg)
                sN[0][(quad * 4 + rg) * 68 + nt * 16 + m16] = acc[nt][rg];
        __builtin_amdgcn_wave_barrier();
        routing(sN[0], sH0, sE0, sA[0], false, &out[((long)branch * B + b) * 64]);
    }
}

extern "C" void kernel_launch(void* const* d_in, const int* in_sizes, int n_in,
                              void* d_out, int out_size, void* d_ws, size_t ws_size,
                              hipStream_t stream) {
    const float* user_table = (const float*)d_in[0];
    const float* item_table = (const float*)d_in[1];
    const float* W0u = (const float*)d_in[2];
    const float* W0i = (const float*)d_in[3];
    const float* W1u = (const float*)d_in[4];
    const float* W1i = (const float*)d_in[5];
    const int* uidx0 = (const int*)d_in[6];
    const int* uidx1 = (const int*)d_in[7];
    const int* uidx2 = (const int*)d_in[8];
    const int* iidx0 = (const int*)d_in[9];
    const int* iidx1 = (const int*)d_in[10];
    const int* iidx2 = (const int*)d_in[11];
    float* out = (float*)d_out;
    short* pk = (short*)d_ws;   // 4 matrices * 16 frags * 64 lanes * 16B = 64 KB

    const int B = in_sizes[6];  // 2048
    hipLaunchKernelGGL(pack_weights, dim3(4), dim3(256), 0, stream,
                       W0u, W0i, W1u, W1i, pk);
    dim3 grid(B, 2), block(NTH);
    hipLaunchKernelGGL(disenhan_mfma, grid, block, 0, stream,
                       user_table, item_table, (const bf16x8*)pk,
                       uidx0, uidx1, uidx2, iidx0, iidx1, iidx2, out, B);
}